// Round 1
// baseline (72.824 us; speedup 1.0000x reference)
//
#include <hip/hip_runtime.h>
#include <math.h>

// Bahdanau attention, fp32. B=4, TQ=TV=256, H=D=512, U=256.
// out = [context (4*256*512)] ++ [attn (4*256*256)]

typedef float f4 __attribute__((ext_vector_type(4)));
typedef float f2 __attribute__((ext_vector_type(2)));

#define B_   4
#define TQ_  256
#define TV_  256
#define H_   512
#define D_   512
#define U_   256
#define KDIM 512           // H == D == 512
#define MROWS 1024         // B*TQ == B*TV

#define C2LOG2E 2.8853900817779268f   // 2*log2(e): exp(2x) = exp2(x*C2LOG2E)
#define LOG2E   1.4426950408889634f

#if __has_builtin(__builtin_amdgcn_exp2f)
#define EXP2F(x) __builtin_amdgcn_exp2f(x)
#else
#define EXP2F(x) exp2f(x)
#endif
#if __has_builtin(__builtin_amdgcn_rcpf)
#define RCPF(x) __builtin_amdgcn_rcpf(x)
#else
#define RCPF(x) (1.0f / (x))
#endif

// ---------------- projection GEMM ----------------
// C[1024,256] = A[1024,512] @ W[512,256] + bias.  blockIdx.z: 0 -> Qp, 1 -> Vp
// 64x64 tile, BK=16, 256 threads, 4x4 micro-tile.
__global__ __launch_bounds__(256) void proj_gemm(
    const float* __restrict__ query, const float* __restrict__ values,
    const float* __restrict__ W1, const float* __restrict__ b1,
    const float* __restrict__ W2, const float* __restrict__ b2,
    float* __restrict__ Qp, float* __restrict__ Vp)
{
    const float* A  = blockIdx.z ? values : query;
    const float* W  = blockIdx.z ? W2 : W1;
    const float* bs = blockIdx.z ? b2 : b1;
    float* C        = blockIdx.z ? Vp : Qp;

    __shared__ __align__(16) float As[16][68];   // As[k][m], +4 pad kills write conflicts
    __shared__ __align__(16) float Bs[16][68];   // Bs[k][n]

    const int tid = threadIdx.x;
    const int tx = tid & 15, ty = tid >> 4;
    const int m0 = blockIdx.y * 64;
    const int n0 = blockIdx.x * 64;

    const int lk = tid & 15;        // k for A-load
    const int lm = tid >> 4;        // row group 0..15
    const int wn = tid & 63;        // n for W-load
    const int wk = tid >> 6;        // 0..3

    float acc[4][4] = {};

    for (int k0 = 0; k0 < KDIM; k0 += 16) {
        #pragma unroll
        for (int j = 0; j < 4; ++j)
            As[lk][lm + 16 * j] = A[(size_t)(m0 + lm + 16 * j) * KDIM + k0 + lk];
        #pragma unroll
        for (int j = 0; j < 4; ++j)
            Bs[wk + 4 * j][wn] = W[(size_t)(k0 + wk + 4 * j) * U_ + n0 + wn];
        __syncthreads();
        #pragma unroll
        for (int kk = 0; kk < 16; ++kk) {
            f4 av = *(const f4*)&As[kk][ty * 4];
            f4 bv = *(const f4*)&Bs[kk][tx * 4];
            #pragma unroll
            for (int i = 0; i < 4; ++i)
                #pragma unroll
                for (int j = 0; j < 4; ++j)
                    acc[i][j] = fmaf(av[i], bv[j], acc[i][j]);
        }
        __syncthreads();
    }

    f4 bias = *(const f4*)&bs[n0 + tx * 4];
    #pragma unroll
    for (int i = 0; i < 4; ++i) {
        f4 o;
        #pragma unroll
        for (int j = 0; j < 4; ++j) o[j] = acc[i][j] + bias[j];
        *(f4*)&C[(size_t)(m0 + ty * 4 + i) * U_ + n0 + tx * 4] = o;
    }
}

// ---------------- fused score + softmax + context ----------------
// One block = (batch b, 4 consecutive q rows). 256 threads.
// Phase 1: thread t owns v=t, computes 4 scores (dot over U with tanh).
// Phase 2: wave w softmaxes q-row w. Phase 3: thread t owns d=2t,2t+1.
__global__ __launch_bounds__(256) void fused_attn(
    const float* __restrict__ Qp, const float* __restrict__ Vp,
    const float* __restrict__ values, const float* __restrict__ Vw,
    const float* __restrict__ bV, float* __restrict__ out)
{
    __shared__ __align__(16) float qrow[4][U_];     // pre-scaled by 2*log2e
    __shared__ __align__(16) float vw_lds[U_];
    __shared__ __align__(16) float attn_lds[4][TV_];

    const int tid = threadIdx.x;
    const int b  = blockIdx.y;
    const int q0 = blockIdx.x * 4;

    #pragma unroll
    for (int qi = 0; qi < 4; ++qi)
        qrow[qi][tid] = Qp[((size_t)(b * TQ_ + q0 + qi)) * U_ + tid] * C2LOG2E;
    vw_lds[tid] = Vw[tid];
    __syncthreads();

    // sum of Vw (constant part of the tanh decomposition)
    const f4* vw4 = (const f4*)vw_lds;
    float sumvw = 0.f;
    #pragma unroll 8
    for (int u4 = 0; u4 < U_ / 4; ++u4) {
        f4 w = vw4[u4];
        sumvw += w[0] + w[1] + w[2] + w[3];
    }

    // ---- scores: sc_qi = sum_u Vw[u] / (exp(2x)+1);  score = sumvw+bV - 2*sc
    float sc0 = 0.f, sc1 = 0.f, sc2 = 0.f, sc3 = 0.f;
    const f4* vrow = (const f4*)&Vp[((size_t)(b * TV_ + tid)) * U_];
    const f4* q40 = (const f4*)&qrow[0][0];
    const f4* q41 = (const f4*)&qrow[1][0];
    const f4* q42 = (const f4*)&qrow[2][0];
    const f4* q43 = (const f4*)&qrow[3][0];
    #pragma unroll 2
    for (int u4 = 0; u4 < U_ / 4; ++u4) {
        f4 vv = vrow[u4] * C2LOG2E;
        f4 w  = vw4[u4];
        f4 a0 = q40[u4], a1 = q41[u4], a2 = q42[u4], a3 = q43[u4];
        #pragma unroll
        for (int j = 0; j < 4; ++j) {
            float e, r;
            e = EXP2F(a0[j] + vv[j]); r = RCPF(e + 1.f); sc0 = fmaf(w[j], r, sc0);
            e = EXP2F(a1[j] + vv[j]); r = RCPF(e + 1.f); sc1 = fmaf(w[j], r, sc1);
            e = EXP2F(a2[j] + vv[j]); r = RCPF(e + 1.f); sc2 = fmaf(w[j], r, sc2);
            e = EXP2F(a3[j] + vv[j]); r = RCPF(e + 1.f); sc3 = fmaf(w[j], r, sc3);
        }
    }
    const float base = sumvw + bV[0];
    attn_lds[0][tid] = base - 2.f * sc0;
    attn_lds[1][tid] = base - 2.f * sc1;
    attn_lds[2][tid] = base - 2.f * sc2;
    attn_lds[3][tid] = base - 2.f * sc3;
    __syncthreads();

    // ---- softmax: wave w handles q-row w (4 rows, 4 waves)
    {
        const int w = tid >> 6, lane = tid & 63;
        float s0 = attn_lds[w][lane];
        float s1 = attn_lds[w][lane + 64];
        float s2 = attn_lds[w][lane + 128];
        float s3 = attn_lds[w][lane + 192];
        float m = fmaxf(fmaxf(s0, s1), fmaxf(s2, s3));
        #pragma unroll
        for (int off = 32; off; off >>= 1) m = fmaxf(m, __shfl_xor(m, off));
        float e0 = EXP2F((s0 - m) * LOG2E);
        float e1 = EXP2F((s1 - m) * LOG2E);
        float e2 = EXP2F((s2 - m) * LOG2E);
        float e3 = EXP2F((s3 - m) * LOG2E);
        float sum = e0 + e1 + e2 + e3;
        #pragma unroll
        for (int off = 32; off; off >>= 1) sum += __shfl_xor(sum, off);
        const float rinv = 1.0f / sum;   // exact division (softmax must sum to 1)
        e0 *= rinv; e1 *= rinv; e2 *= rinv; e3 *= rinv;
        attn_lds[w][lane]       = e0;
        attn_lds[w][lane + 64]  = e1;
        attn_lds[w][lane + 128] = e2;
        attn_lds[w][lane + 192] = e3;
        float* attn_out = out + (size_t)B_ * TQ_ * D_;
        const size_t rb = ((size_t)(b * TQ_ + q0 + w)) * TV_;
        attn_out[rb + lane]       = e0;
        attn_out[rb + lane + 64]  = e1;
        attn_out[rb + lane + 128] = e2;
        attn_out[rb + lane + 192] = e3;
    }
    __syncthreads();

    // ---- context: thread t owns d = 2t, 2t+1 for all 4 q rows
    f2 acc0 = {0.f, 0.f}, acc1 = {0.f, 0.f}, acc2 = {0.f, 0.f}, acc3 = {0.f, 0.f};
    const f2* vals2 = (const f2*)&values[(size_t)b * TV_ * D_];
    #pragma unroll 4
    for (int v = 0; v < TV_; ++v) {
        f2 vv = vals2[(size_t)v * (D_ / 2) + tid];
        float a0 = attn_lds[0][v], a1 = attn_lds[1][v];
        float a2 = attn_lds[2][v], a3 = attn_lds[3][v];
        acc0 += a0 * vv;
        acc1 += a1 * vv;
        acc2 += a2 * vv;
        acc3 += a3 * vv;
    }
    *(f2*)&out[((size_t)(b * TQ_ + q0 + 0)) * D_ + 2 * tid] = acc0;
    *(f2*)&out[((size_t)(b * TQ_ + q0 + 1)) * D_ + 2 * tid] = acc1;
    *(f2*)&out[((size_t)(b * TQ_ + q0 + 2)) * D_ + 2 * tid] = acc2;
    *(f2*)&out[((size_t)(b * TQ_ + q0 + 3)) * D_ + 2 * tid] = acc3;
}

extern "C" void kernel_launch(void* const* d_in, const int* in_sizes, int n_in,
                              void* d_out, int out_size, void* d_ws, size_t ws_size,
                              hipStream_t stream) {
    const float* query  = (const float*)d_in[0];
    const float* values = (const float*)d_in[1];
    const float* W1     = (const float*)d_in[2];
    const float* b1     = (const float*)d_in[3];
    const float* W2     = (const float*)d_in[4];
    const float* b2     = (const float*)d_in[5];
    const float* Vw     = (const float*)d_in[6];
    const float* bV     = (const float*)d_in[7];
    float* out = (float*)d_out;

    float* Qp = (float*)d_ws;                  // [1024,256] = 1 MB
    float* Vp = Qp + (size_t)MROWS * U_;       // [1024,256] = 1 MB

    proj_gemm<<<dim3(U_ / 64, MROWS / 64, 2), 256, 0, stream>>>(
        query, values, W1, b1, W2, b2, Qp, Vp);
    fused_attn<<<dim3(TQ_ / 4, B_), 256, 0, stream>>>(
        Qp, Vp, values, Vw, bV, out);
}

// Round 3
// 58.393 us; speedup vs baseline: 1.2471x; 1.2471x over previous
//
#include <hip/hip_runtime.h>
#include <math.h>

// Bahdanau attention, fp32. B=4, TQ=TV=256, H=D=512, U=256.
// out = [context (4*256*512)] ++ [attn (4*256*256)]
//
// Key algebraic trick: tanh(x) = 1 - 2/(e^{2x}+1), and e^{2(q+v)} = e^{2q}*e^{2v}.
// Projection epilogue stores Eq = exp2(C*Qp), Ev = exp2(C*Vp); the score loop then
// needs only ONE transcendental (rcp) per element. The additive constant
// (sum(Vw) + bV) cancels in softmax and is dropped.

typedef float f4 __attribute__((ext_vector_type(4)));
typedef float f2 __attribute__((ext_vector_type(2)));

#define B_   4
#define TQ_  256
#define TV_  256
#define D_   512
#define U_   256
#define KDIM 512           // H == D == 512
#define MROWS 1024         // B*TQ == B*TV
#define BKP  32            // proj K-tile

#define C2LOG2E 2.8853900817779268f   // 2*log2(e)

#if __has_builtin(__builtin_amdgcn_exp2f)
#define EXP2F(x) __builtin_amdgcn_exp2f(x)
#else
#define EXP2F(x) exp2f(x)
#endif
#if __has_builtin(__builtin_amdgcn_rcpf)
#define RCPF(x) __builtin_amdgcn_rcpf(x)
#else
#define RCPF(x) (1.0f / (x))
#endif

// ---------------- projection GEMM + exp epilogue ----------------
// E[1024,256] = exp2(C2LOG2E * (A[1024,512] @ W[512,256] + bias))
// blockIdx.z: 0 -> Eq (query,W1,b1), 1 -> Ev (values,W2,b2)
// 64x64 tile, BK=32, 256 threads, 4x4 micro-tile, register-prefetch dbuf.
__global__ __launch_bounds__(256) void proj_gemm(
    const float* __restrict__ query, const float* __restrict__ values,
    const float* __restrict__ W1, const float* __restrict__ b1,
    const float* __restrict__ W2, const float* __restrict__ b2,
    float* __restrict__ Eq, float* __restrict__ Ev)
{
    const float* A  = blockIdx.z ? values : query;
    const float* W  = blockIdx.z ? W2 : W1;
    const float* bs = blockIdx.z ? b2 : b1;
    float* E        = blockIdx.z ? Ev : Eq;

    __shared__ __align__(16) float As[BKP][68];   // [k][m] (transposed store)
    __shared__ __align__(16) float Bs[BKP][68];   // [k][n]

    const int tid = threadIdx.x;
    const int tx = tid & 15, ty = tid >> 4;
    const int m0 = blockIdx.y * 64;
    const int n0 = blockIdx.x * 64;

    // A-load: thread covers A[m0+am][k0+ak .. k0+ak+7] (two f4 along k)
    const int am = tid >> 2;
    const int ak = (tid & 3) * 8;
    // W-load: thread covers W[k0+wk][n0+wn .. +7] (two f4 along n)
    const int wk = tid >> 3;
    const int wn = (tid & 7) * 8;

    const float* Arow = A + (size_t)(m0 + am) * KDIM + ak;
    const float* Wrow = W + (size_t)wk * U_ + n0 + wn;

    f4 pa0 = *(const f4*)(Arow);
    f4 pa1 = *(const f4*)(Arow + 4);
    f4 pb0 = *(const f4*)(Wrow);
    f4 pb1 = *(const f4*)(Wrow + 4);

    float acc[4][4] = {};

    const int NSTEP = KDIM / BKP;   // 16
    for (int s = 0; s < NSTEP; ++s) {
        __syncthreads();   // prior iteration done reading LDS
        #pragma unroll
        for (int j = 0; j < 4; ++j) {
            As[ak + j][am]     = pa0[j];
            As[ak + 4 + j][am] = pa1[j];
        }
        *(f4*)&Bs[wk][wn]     = pb0;
        *(f4*)&Bs[wk][wn + 4] = pb1;
        __syncthreads();

        if (s + 1 < NSTEP) {     // prefetch next K-tile into regs (lands during compute)
            const float* An = Arow + (size_t)(s + 1) * BKP;
            const float* Wn = Wrow + (size_t)(s + 1) * BKP * U_;
            pa0 = *(const f4*)(An);
            pa1 = *(const f4*)(An + 4);
            pb0 = *(const f4*)(Wn);
            pb1 = *(const f4*)(Wn + 4);
        }

        #pragma unroll
        for (int kk = 0; kk < BKP; ++kk) {
            f4 av = *(const f4*)&As[kk][ty * 4];
            f4 bv = *(const f4*)&Bs[kk][tx * 4];
            #pragma unroll
            for (int i = 0; i < 4; ++i)
                #pragma unroll
                for (int j = 0; j < 4; ++j)
                    acc[i][j] = fmaf(av[i], bv[j], acc[i][j]);
        }
    }

    f4 bias = *(const f4*)&bs[n0 + tx * 4];
    #pragma unroll
    for (int i = 0; i < 4; ++i) {
        f4 o;
        #pragma unroll
        for (int j = 0; j < 4; ++j)
            o[j] = EXP2F((acc[i][j] + bias[j]) * C2LOG2E);
        *(f4*)&E[(size_t)(m0 + ty * 4 + i) * U_ + n0 + tx * 4] = o;
    }
}

// ---------------- fused score + softmax + context ----------------
// One block = (batch b, 4 consecutive q rows). 512 threads (8 waves).
// Score: thread t owns v = t&255, u-half = t>>8; partials combined in LDS.
// Softmax: wave w < 4 handles q-row w. Context: half-block per q-row pair.
__global__ __launch_bounds__(512) void fused_attn(
    const float* __restrict__ Eq, const float* __restrict__ Ev,
    const float* __restrict__ values, const float* __restrict__ Vw,
    float* __restrict__ out)
{
    __shared__ __align__(16) float eq[4][U_];       // Eq rows for the 4 q's
    __shared__ __align__(16) float vw[U_];
    __shared__ __align__(16) float scr[2][4][TV_];  // score partials -> attn

    const int tid = threadIdx.x;
    const int b  = blockIdx.y;
    const int q0 = blockIdx.x * 4;

    // rows q0..q0+3 are contiguous: flat copy 1024 floats as f2
    {
        const f2* src = (const f2*)(Eq + (size_t)(b * TQ_ + q0) * U_);
        ((f2*)eq)[tid] = src[tid];
    }
    if (tid < U_) vw[tid] = Vw[tid];
    __syncthreads();

    const int v  = tid & 255;
    const int uh = tid >> 8;          // u-half: [uh*128, uh*128+128)

    // ---- scores: p = sum_u Vw[u] / (Eq[q,u]*Ev[v,u] + 1)   (score = const - 2p)
    {
        const f4* evp = (const f4*)&Ev[((size_t)(b * TV_ + v)) * U_ + uh * 128];
        const f4* q40 = (const f4*)&eq[0][uh * 128];
        const f4* q41 = (const f4*)&eq[1][uh * 128];
        const f4* q42 = (const f4*)&eq[2][uh * 128];
        const f4* q43 = (const f4*)&eq[3][uh * 128];
        const f4* vwp = (const f4*)&vw[uh * 128];

        float sc0 = 0.f, sc1 = 0.f, sc2 = 0.f, sc3 = 0.f;
        #pragma unroll 4
        for (int i = 0; i < 32; ++i) {
            f4 ev4 = evp[i];
            f4 w4  = vwp[i];
            f4 a0 = q40[i], a1 = q41[i], a2 = q42[i], a3 = q43[i];
            #pragma unroll
            for (int j = 0; j < 4; ++j) {
                float e, r;
                e = a0[j] * ev4[j]; r = RCPF(e + 1.f); sc0 = fmaf(w4[j], r, sc0);
                e = a1[j] * ev4[j]; r = RCPF(e + 1.f); sc1 = fmaf(w4[j], r, sc1);
                e = a2[j] * ev4[j]; r = RCPF(e + 1.f); sc2 = fmaf(w4[j], r, sc2);
                e = a3[j] * ev4[j]; r = RCPF(e + 1.f); sc3 = fmaf(w4[j], r, sc3);
            }
        }
        scr[uh][0][v] = sc0;
        scr[uh][1][v] = sc1;
        scr[uh][2][v] = sc2;
        scr[uh][3][v] = sc3;
    }
    __syncthreads();

    // ---- softmax over v: wave w handles q-row w.  s = -2p (+const, cancels)
    {
        const int w = tid >> 6, lane = tid & 63;
        if (w < 4) {
            float p0 = scr[0][w][lane]       + scr[1][w][lane];
            float p1 = scr[0][w][lane + 64]  + scr[1][w][lane + 64];
            float p2 = scr[0][w][lane + 128] + scr[1][w][lane + 128];
            float p3 = scr[0][w][lane + 192] + scr[1][w][lane + 192];
            float m = fminf(fminf(p0, p1), fminf(p2, p3));   // max score = min p
            #pragma unroll
            for (int off = 32; off; off >>= 1) m = fminf(m, __shfl_xor(m, off));
            float e0 = EXP2F((m - p0) * C2LOG2E);
            float e1 = EXP2F((m - p1) * C2LOG2E);
            float e2 = EXP2F((m - p2) * C2LOG2E);
            float e3 = EXP2F((m - p3) * C2LOG2E);
            float sum = e0 + e1 + e2 + e3;
            #pragma unroll
            for (int off = 32; off; off >>= 1) sum += __shfl_xor(sum, off);
            const float rinv = 1.0f / sum;    // exact division
            e0 *= rinv; e1 *= rinv; e2 *= rinv; e3 *= rinv;
            scr[0][w][lane]       = e0;
            scr[0][w][lane + 64]  = e1;
            scr[0][w][lane + 128] = e2;
            scr[0][w][lane + 192] = e3;
            float* attn_out = out + (size_t)B_ * TQ_ * D_;
            const size_t rb = ((size_t)(b * TQ_ + q0 + w)) * TV_;
            attn_out[rb + lane]       = e0;
            attn_out[rb + lane + 64]  = e1;
            attn_out[rb + lane + 128] = e2;
            attn_out[rb + lane + 192] = e3;
        }
    }
    __syncthreads();

    // ---- context: half-block qh owns q-rows {2qh, 2qh+1}; thread owns d = 2*d2
    {
        const int qh = tid >> 8;
        const int d2 = tid & 255;
        const int r0 = 2 * qh, r1 = 2 * qh + 1;
        f2 acc0 = {0.f, 0.f}, acc1 = {0.f, 0.f};
        const f2* vals2 = (const f2*)&values[(size_t)b * TV_ * D_];
        #pragma unroll 4
        for (int vv = 0; vv < TV_; ++vv) {
            f2 val = vals2[(size_t)vv * (D_ / 2) + d2];
            acc0 += scr[0][r0][vv] * val;
            acc1 += scr[0][r1][vv] * val;
        }
        *(f2*)&out[((size_t)(b * TQ_ + q0 + r0)) * D_ + 2 * d2] = acc0;
        *(f2*)&out[((size_t)(b * TQ_ + q0 + r1)) * D_ + 2 * d2] = acc1;
    }
}

extern "C" void kernel_launch(void* const* d_in, const int* in_sizes, int n_in,
                              void* d_out, int out_size, void* d_ws, size_t ws_size,
                              hipStream_t stream) {
    const float* query  = (const float*)d_in[0];
    const float* values = (const float*)d_in[1];
    const float* W1     = (const float*)d_in[2];
    const float* b1     = (const float*)d_in[3];
    const float* W2     = (const float*)d_in[4];
    const float* b2     = (const float*)d_in[5];
    const float* Vw     = (const float*)d_in[6];
    float* out = (float*)d_out;

    float* Eq = (float*)d_ws;                  // exp2(C*(query@W1+b1)) [1024,256]
    float* Ev = Eq + (size_t)MROWS * U_;       // exp2(C*(values@W2+b2)) [1024,256]

    proj_gemm<<<dim3(U_ / 64, MROWS / 64, 2), 256, 0, stream>>>(
        query, values, W1, b1, W2, b2, Eq, Ev);
    fused_attn<<<dim3(TQ_ / 4, B_), 512, 0, stream>>>(
        Eq, Ev, values, Vw, out);
}